// Round 4
// baseline (371344.702 us; speedup 1.0000x reference)
//
#include <hip/hip_runtime.h>

// NeuralODESIR round 4: spill-free fp64-MAC kernel.
// Round-3 post-mortem: VGPR_Count=212 < 256 needed for h1[64]+acc[64] both f64
// -> allocator spilled to scratch, occupancy fell to 1 wave/SIMD, VALUBusy 26%.
// Round-2 datum proves fp32-stored activations + exact (fp64) MACs hit the
// absmax floor (0.01953125, ref-side error). So: h1 stored fp32 (64 VGPR),
// acc f64 (128 VGPR), cvt on the fly in the layer-2 dot. ~230 VGPR -> 2
// waves/SIMD, no scratch.

#define NW1  (5 * 64)
#define NB1  64
#define NW2  (64 * 128)
#define NB2  128
#define NW3  (128 * 64)
#define NB3  64
#define NW4  (64 * 3)
#define NB4  3

// offsets (in doubles) inside d_ws
#define oW1  0
#define oB1  (oW1 + NW1)       // 320
#define oW2T (oB1 + NB1)       // 384
#define oB2  (oW2T + NW2)      // 8576
#define oW3  (oB2 + NB2)       // 8704
#define oB3  (oW3 + NW3)       // 16896
#define oW4  (oB3 + NB3)       // 16960
#define oB4  (oW4 + NW4)       // 17152
#define NTOT (oB4 + NB4)       // 17155

// fp64 tanh, |abs err| ~ 1e-12. tanh(x) = sign(x) * (1 - 2/(exp(2|x|)+1)).
__device__ __forceinline__ double tanh64(double x) {
    const double TWO_LOG2E = 2.885390081777926814; // 2*log2(e)
    double ax = fabs(x);
    ax = fmin(ax, 20.0);
    double u = ax * TWO_LOG2E;
    double n = rint(u);
    double f = u - n;                    // |f| <= 0.5
    double p =            1.0178086009239697e-7;   // ln2^9/9!
    p = fma(p, f, 1.3215486790144305e-6);
    p = fma(p, f, 1.5252733804059838e-5);
    p = fma(p, f, 1.5403530393381606e-4);
    p = fma(p, f, 1.3333558146428443e-3);
    p = fma(p, f, 9.6181291076284772e-3);
    p = fma(p, f, 5.5504108664821580e-2);
    p = fma(p, f, 2.4022650695910071e-1);
    p = fma(p, f, 6.9314718055994531e-1);
    p = fma(p, f, 1.0);
    double E  = ldexp(p, (int)n);        // exp(2|x|) >= 1
    double D  = E + 1.0;
    double r0 = (double)__builtin_amdgcn_rcpf((float)D);
    double r1 = r0 * fma(-D, r0, 2.0);
    double q0 = 2.0 * r1;
    double q  = fma(r1, fma(-D, q0, 2.0), q0);     // 2/D to ~1 ulp
    double t  = 1.0 - q;
    return copysign(t, x);
}

__device__ __forceinline__ void store_softmax(float* __restrict__ out, size_t base,
                                              float a, float b, float c) {
    float m  = fmaxf(a, fmaxf(b, c));
    float e0 = expf(a - m);
    float e1 = expf(b - m);
    float e2 = expf(c - m);
    float s  = e0 + e1 + e2;
    out[base + 0] = e0 / s;
    out[base + 1] = e1 / s;
    out[base + 2] = e2 / s;
}

// Weights fp64 in ws; W2 pre-transposed to [128][64].
__device__ __forceinline__ void mlp_eval(
    double zs, double zi, double zr, double be, double ga,
    const double* __restrict__ W1, const double* __restrict__ b1,
    const double* __restrict__ W2, const double* __restrict__ b2,
    const double* __restrict__ W3, const double* __restrict__ b3,
    const double* __restrict__ W4, const double* __restrict__ b4,
    double& d0, double& d1, double& d2)
{
    // h1 stored fp32: 64 VGPR instead of 128. Proven precision-safe (round 2).
    float h1[64];
    #pragma unroll
    for (int j = 0; j < 64; ++j) {
        double t = b1[j];
        t = fma(W1[0 * 64 + j], zs, t);
        t = fma(W1[1 * 64 + j], zi, t);
        t = fma(W1[2 * 64 + j], zr, t);
        t = fma(W1[3 * 64 + j], be, t);
        t = fma(W1[4 * 64 + j], ga, t);
        h1[j] = (float)tanh64(t);
    }

    double acc[64];
    #pragma unroll
    for (int j = 0; j < 64; ++j) acc[j] = b3[j];

    #pragma unroll 2
    for (int k = 0; k < 128; ++k) {
        const double* w2k = W2 + (size_t)k * 64;   // contiguous row of W2^T
        // 4 independent chains; products exact: (double)fp32 * f64 weight
        double t0 = b2[k], t1 = 0.0, t2 = 0.0, t3 = 0.0;
        #pragma unroll
        for (int i = 0; i < 64; i += 4) {
            t0 = fma(w2k[i + 0], (double)h1[i + 0], t0);
            t1 = fma(w2k[i + 1], (double)h1[i + 1], t1);
            t2 = fma(w2k[i + 2], (double)h1[i + 2], t2);
            t3 = fma(w2k[i + 3], (double)h1[i + 3], t3);
        }
        double h = tanh64((t0 + t1) + (t2 + t3));
        const double* w3k = W3 + (size_t)k * 64;
        #pragma unroll
        for (int j = 0; j < 64; ++j) acc[j] = fma(w3k[j], h, acc[j]);
    }

    double e0 = b4[0], e1 = b4[1], e2 = b4[2];
    #pragma unroll
    for (int j = 0; j < 64; ++j) {
        double h = tanh64(acc[j]);
        e0 = fma(W4[j * 3 + 0], h, e0);
        e1 = fma(W4[j * 3 + 1], h, e1);
        e2 = fma(W4[j * 3 + 2], h, e2);
    }
    d0 = e0; d1 = e1; d2 = e2;
}

__global__ __launch_bounds__(256, 2) void sir_rk4_kernel(
    const float* __restrict__ y0,   const float* __restrict__ tspan,
    const float* __restrict__ beta, const float* __restrict__ gamma,
    const double* __restrict__ W1,  const double* __restrict__ b1,
    const double* __restrict__ W2,  const double* __restrict__ b2,
    const double* __restrict__ W3,  const double* __restrict__ b3,
    const double* __restrict__ W4,  const double* __restrict__ b4,
    float* __restrict__ out, int B, int T)
{
    int b = blockIdx.x * blockDim.x + threadIdx.x;
    if (b >= B) return;

    double ys = (double)y0[b * 3 + 0];
    double yi = (double)y0[b * 3 + 1];
    double yr = (double)y0[b * 3 + 2];
    double be = (double)beta[b];
    double ga = (double)gamma[b];

    store_softmax(out, (size_t)b * 3, (float)ys, (float)yi, (float)yr);

    #pragma unroll 1
    for (int t = 0; t < T - 1; ++t) {
        double dt = (double)tspan[t + 1] - (double)tspan[t];

        double ks0 = 0.0, ks1 = 0.0, ks2 = 0.0;
        double zs = ys, zi = yi, zr = yr;

        #pragma unroll 1
        for (int st = 0; st < 4; ++st) {
            double d0, d1, d2;
            mlp_eval(zs, zi, zr, be, ga,
                     W1, b1, W2, b2, W3, b3, W4, b4, d0, d1, d2);
            double w = (st == 1 || st == 2) ? 2.0 : 1.0;
            ks0 = fma(w, d0, ks0);
            ks1 = fma(w, d1, ks1);
            ks2 = fma(w, d2, ks2);
            double a = (st < 2) ? 0.5 * dt : dt;
            zs = fma(a, d0, ys);
            zi = fma(a, d1, yi);
            zr = fma(a, d2, yr);
        }

        double c = dt * (1.0 / 6.0);
        ys = fma(c, ks0, ys);
        yi = fma(c, ks1, yi);
        yr = fma(c, ks2, yr);

        store_softmax(out, ((size_t)(t + 1) * B + b) * 3, (float)ys, (float)yi, (float)yr);
    }
}

// widen all params to fp64 in ws; W2 transposed to [128][64]
__global__ void stage_params_kernel(
    const float* __restrict__ W1, const float* __restrict__ b1,
    const float* __restrict__ W2, const float* __restrict__ b2,
    const float* __restrict__ W3, const float* __restrict__ b3,
    const float* __restrict__ W4, const float* __restrict__ b4,
    double* __restrict__ P)
{
    int idx = blockIdx.x * blockDim.x + threadIdx.x;
    if (idx >= NTOT) return;
    float v;
    if (idx < oB1)       v = W1[idx - oW1];
    else if (idx < oW2T) v = b1[idx - oB1];
    else if (idx < oB2)  { int u = idx - oW2T; int k = u / 64; int i = u % 64; v = W2[i * 128 + k]; }
    else if (idx < oW3)  v = b2[idx - oB2];
    else if (idx < oB3)  v = W3[idx - oW3];
    else if (idx < oW4)  v = b3[idx - oB3];
    else if (idx < oB4)  v = W4[idx - oW4];
    else                 v = b4[idx - oB4];
    P[idx] = (double)v;
}

extern "C" void kernel_launch(void* const* d_in, const int* in_sizes, int n_in,
                              void* d_out, int out_size, void* d_ws, size_t ws_size,
                              hipStream_t stream) {
    const float* y0    = (const float*)d_in[0];
    const float* tspan = (const float*)d_in[1];
    const float* beta  = (const float*)d_in[2];
    const float* gamma = (const float*)d_in[3];
    const float* W1    = (const float*)d_in[4];
    const float* b1    = (const float*)d_in[5];
    const float* W2    = (const float*)d_in[6];
    const float* b2    = (const float*)d_in[7];
    const float* W3    = (const float*)d_in[8];
    const float* b3    = (const float*)d_in[9];
    const float* W4    = (const float*)d_in[10];
    const float* b4    = (const float*)d_in[11];

    int B = in_sizes[0] / 3;
    int T = in_sizes[1];
    float* out = (float*)d_out;

    int blocks = (B + 255) / 256;

    double* P = (double*)d_ws;
    stage_params_kernel<<<(NTOT + 255) / 256, 256, 0, stream>>>(
        W1, b1, W2, b2, W3, b3, W4, b4, P);
    sir_rk4_kernel<<<blocks, 256, 0, stream>>>(
        y0, tspan, beta, gamma,
        P + oW1, P + oB1, P + oW2T, P + oB2,
        P + oW3, P + oB3, P + oW4,  P + oB4, out, B, T);
}

// Round 5
// 157248.425 us; speedup vs baseline: 2.3615x; 2.3615x over previous
//
#include <hip/hip_runtime.h>

// NeuralODESIR round 5: spill-free f64-MAC kernel, fp32 tanh.
// r4 post-mortem: __launch_bounds__(256,2) capped VGPR at 128 < ~230 live
//   -> scratch spill -> 850 GB/dispatch HBM thrash (FETCH_SIZE), 371 ms.
// r2/r3 datum: absmax 0.01953125 bit-identical for fp32-tanhf and 1e-12 f64
//   tanh -> floor is reference-side; fp32 tanhf + exact f64 MACs suffice.
// Fixes: (1) launch_bounds(256,1) so the allocator takes the ~230 VGPRs it
//   needs (<=256 -> 2 waves/SIMD, zero scratch); (2) fp32 tanhf (frees the
//   f64 tanh's ~27% pipe share); (3) keep 4-chain dot + unroll-2 for ILP.

#define NW1  (5 * 64)
#define NB1  64
#define NW2  (64 * 128)
#define NB2  128
#define NW3  (128 * 64)
#define NB3  64
#define NW4  (64 * 3)
#define NB4  3

// offsets (in doubles) inside d_ws
#define oW1  0
#define oB1  (oW1 + NW1)       // 320
#define oW2T (oB1 + NB1)       // 384
#define oB2  (oW2T + NW2)      // 8576
#define oW3  (oB2 + NB2)       // 8704
#define oB3  (oW3 + NW3)       // 16896
#define oW4  (oB3 + NB3)       // 16960
#define oB4  (oW4 + NW4)       // 17152
#define NTOT (oB4 + NB4)       // 17155

__device__ __forceinline__ void store_softmax(float* __restrict__ out, size_t base,
                                              float a, float b, float c) {
    float m  = fmaxf(a, fmaxf(b, c));
    float e0 = expf(a - m);
    float e1 = expf(b - m);
    float e2 = expf(c - m);
    float s  = e0 + e1 + e2;
    out[base + 0] = e0 / s;
    out[base + 1] = e1 / s;
    out[base + 2] = e2 / s;
}

// Weights fp64 in ws; W2 pre-transposed to [128][64].
// Numerics = round-2 (proven at the 0.01953125 floor): every MAC is
// v_fma_f64 with an exact (double)fp32 * f64 product; activations are fp32
// tanhf of the fp32-rounded pre-activation.
__device__ __forceinline__ void mlp_eval(
    double zs, double zi, double zr, double be, double ga,
    const double* __restrict__ W1, const double* __restrict__ b1,
    const double* __restrict__ W2, const double* __restrict__ b2,
    const double* __restrict__ W3, const double* __restrict__ b3,
    const double* __restrict__ W4, const double* __restrict__ b4,
    double& d0, double& d1, double& d2)
{
    float h1[64];                       // fp32 storage: 64 VGPR
    #pragma unroll
    for (int j = 0; j < 64; ++j) {
        double t = b1[j];
        t = fma(W1[0 * 64 + j], zs, t);
        t = fma(W1[1 * 64 + j], zi, t);
        t = fma(W1[2 * 64 + j], zr, t);
        t = fma(W1[3 * 64 + j], be, t);
        t = fma(W1[4 * 64 + j], ga, t);
        h1[j] = tanhf((float)t);
    }

    double acc[64];                     // f64 accumulators: 128 VGPR
    #pragma unroll
    for (int j = 0; j < 64; ++j) acc[j] = b3[j];

    #pragma unroll 2
    for (int k = 0; k < 128; ++k) {
        const double* w2k = W2 + (size_t)k * 64;   // contiguous row of W2^T
        // 4 independent chains -> issue-bound, not latency-bound
        double t0 = b2[k], t1 = 0.0, t2 = 0.0, t3 = 0.0;
        #pragma unroll
        for (int i = 0; i < 64; i += 4) {
            t0 = fma(w2k[i + 0], (double)h1[i + 0], t0);
            t1 = fma(w2k[i + 1], (double)h1[i + 1], t1);
            t2 = fma(w2k[i + 2], (double)h1[i + 2], t2);
            t3 = fma(w2k[i + 3], (double)h1[i + 3], t3);
        }
        double h = (double)tanhf((float)((t0 + t1) + (t2 + t3)));
        const double* w3k = W3 + (size_t)k * 64;
        #pragma unroll
        for (int j = 0; j < 64; ++j) acc[j] = fma(w3k[j], h, acc[j]);
    }

    double e0 = b4[0], e1 = b4[1], e2 = b4[2];
    #pragma unroll
    for (int j = 0; j < 64; ++j) {
        double h = (double)tanhf((float)acc[j]);
        e0 = fma(W4[j * 3 + 0], h, e0);
        e1 = fma(W4[j * 3 + 1], h, e1);
        e2 = fma(W4[j * 3 + 2], h, e2);
    }
    d0 = e0; d1 = e1; d2 = e2;
}

__global__ __launch_bounds__(256, 1) void sir_rk4_kernel(
    const float* __restrict__ y0,   const float* __restrict__ tspan,
    const float* __restrict__ beta, const float* __restrict__ gamma,
    const double* __restrict__ W1,  const double* __restrict__ b1,
    const double* __restrict__ W2,  const double* __restrict__ b2,
    const double* __restrict__ W3,  const double* __restrict__ b3,
    const double* __restrict__ W4,  const double* __restrict__ b4,
    float* __restrict__ out, int B, int T)
{
    int b = blockIdx.x * blockDim.x + threadIdx.x;
    if (b >= B) return;

    double ys = (double)y0[b * 3 + 0];
    double yi = (double)y0[b * 3 + 1];
    double yr = (double)y0[b * 3 + 2];
    double be = (double)beta[b];
    double ga = (double)gamma[b];

    store_softmax(out, (size_t)b * 3, (float)ys, (float)yi, (float)yr);

    #pragma unroll 1
    for (int t = 0; t < T - 1; ++t) {
        double dt = (double)tspan[t + 1] - (double)tspan[t];

        double ks0 = 0.0, ks1 = 0.0, ks2 = 0.0;
        double zs = ys, zi = yi, zr = yr;

        #pragma unroll 1
        for (int st = 0; st < 4; ++st) {
            double d0, d1, d2;
            mlp_eval(zs, zi, zr, be, ga,
                     W1, b1, W2, b2, W3, b3, W4, b4, d0, d1, d2);
            double w = (st == 1 || st == 2) ? 2.0 : 1.0;
            ks0 = fma(w, d0, ks0);
            ks1 = fma(w, d1, ks1);
            ks2 = fma(w, d2, ks2);
            double a = (st < 2) ? 0.5 * dt : dt;
            zs = fma(a, d0, ys);
            zi = fma(a, d1, yi);
            zr = fma(a, d2, yr);
        }

        double c = dt * (1.0 / 6.0);
        ys = fma(c, ks0, ys);
        yi = fma(c, ks1, yi);
        yr = fma(c, ks2, yr);

        store_softmax(out, ((size_t)(t + 1) * B + b) * 3, (float)ys, (float)yi, (float)yr);
    }
}

// widen all params to fp64 in ws; W2 transposed to [128][64]
__global__ void stage_params_kernel(
    const float* __restrict__ W1, const float* __restrict__ b1,
    const float* __restrict__ W2, const float* __restrict__ b2,
    const float* __restrict__ W3, const float* __restrict__ b3,
    const float* __restrict__ W4, const float* __restrict__ b4,
    double* __restrict__ P)
{
    int idx = blockIdx.x * blockDim.x + threadIdx.x;
    if (idx >= NTOT) return;
    float v;
    if (idx < oB1)       v = W1[idx - oW1];
    else if (idx < oW2T) v = b1[idx - oB1];
    else if (idx < oB2)  { int u = idx - oW2T; int k = u / 64; int i = u % 64; v = W2[i * 128 + k]; }
    else if (idx < oW3)  v = b2[idx - oB2];
    else if (idx < oB3)  v = W3[idx - oW3];
    else if (idx < oW4)  v = b3[idx - oB3];
    else if (idx < oB4)  v = W4[idx - oW4];
    else                 v = b4[idx - oB4];
    P[idx] = (double)v;
}

extern "C" void kernel_launch(void* const* d_in, const int* in_sizes, int n_in,
                              void* d_out, int out_size, void* d_ws, size_t ws_size,
                              hipStream_t stream) {
    const float* y0    = (const float*)d_in[0];
    const float* tspan = (const float*)d_in[1];
    const float* beta  = (const float*)d_in[2];
    const float* gamma = (const float*)d_in[3];
    const float* W1    = (const float*)d_in[4];
    const float* b1    = (const float*)d_in[5];
    const float* W2    = (const float*)d_in[6];
    const float* b2    = (const float*)d_in[7];
    const float* W3    = (const float*)d_in[8];
    const float* b3    = (const float*)d_in[9];
    const float* W4    = (const float*)d_in[10];
    const float* b4    = (const float*)d_in[11];

    int B = in_sizes[0] / 3;
    int T = in_sizes[1];
    float* out = (float*)d_out;

    int blocks = (B + 255) / 256;

    double* P = (double*)d_ws;
    stage_params_kernel<<<(NTOT + 255) / 256, 256, 0, stream>>>(
        W1, b1, W2, b2, W3, b3, W4, b4, P);
    sir_rk4_kernel<<<blocks, 256, 0, stream>>>(
        y0, tspan, beta, gamma,
        P + oW1, P + oB1, P + oW2T, P + oB2,
        P + oW3, P + oB3, P + oW4,  P + oB4, out, B, T);
}

// Round 6
// 90814.575 us; speedup vs baseline: 4.0890x; 1.7315x over previous
//
#include <hip/hip_runtime.h>

// NeuralODESIR round 6: occupancy + cvt restructure.
// r5 post-mortem: ~330 total regs/wave (164 VGPR + ~166 AGPR spill) -> 1
// wave/SIMD, VALUBusy 36%; plus 8192 per-use v_cvt_f64_f32 in the inner dot.
// Fixes:
//  - h1 lives in LDS as f32 ([64][128], 32KB/block, own-column access, no
//    barriers). Tiled 8x16 layer-2: each h1 read+cvt happens 8x/eval (512)
//    instead of 8192; inner loops are pure v_fma_f64 with SGPR weights.
//  - h2[16] (32 VGPR) + acc3[64] (128 VGPR) -> ~210 VGPR total;
//    __launch_bounds__(128,2) caps at 256 -> 2 waves/SIMD, 4 blocks/CU.
//  - L1/L4 are dynamic loops through the LDS buffer -> ~15KB I-footprint.
// Numerics = r2/r5 proven: exact f64 MACs, fp32 tanhf of fp32-rounded
// preacts, f64 RK4 state. absmax floor is reference-side (0.01953125).

#define NW1  (5 * 64)
#define NB1  64
#define NW2  (64 * 128)
#define NB2  128
#define NW3  (128 * 64)
#define NB3  64
#define NW4  (64 * 3)
#define NB4  3

// offsets (in doubles) inside d_ws
#define oW1T 0                  // [64][5]  (transposed W1)
#define oB1  (oW1T + NW1)       // 320
#define oW2  (oB1 + NB1)        // 384   [64][128] original layout
#define oB2  (oW2 + NW2)        // 8576
#define oW3  (oB2 + NB2)        // 8704  [128][64] original layout
#define oB3  (oW3 + NW3)        // 16896
#define oW4  (oB3 + NB3)        // 16960 [64][3] original layout
#define oB4  (oW4 + NW4)        // 17152
#define NTOT (oB4 + NB4)        // 17155

__device__ __forceinline__ void store_softmax(float* __restrict__ out, size_t base,
                                              float a, float b, float c) {
    float m  = fmaxf(a, fmaxf(b, c));
    float e0 = expf(a - m);
    float e1 = expf(b - m);
    float e2 = expf(c - m);
    float s  = e0 + e1 + e2;
    out[base + 0] = e0 / s;
    out[base + 1] = e1 / s;
    out[base + 2] = e2 / s;
}

__global__ __launch_bounds__(128, 2) void sir_rk4_kernel(
    const float* __restrict__ y0,   const float* __restrict__ tspan,
    const float* __restrict__ beta, const float* __restrict__ gamma,
    const double* __restrict__ P,
    float* __restrict__ out, int B, int T)
{
    // h1 (layers phase) and h3 (L4 phase) share this buffer.
    // Layout [elem][thread]: lane-consecutive -> conflict-free; each thread
    // touches only its own column -> no __syncthreads needed.
    __shared__ float hbuf[64][128];

    const int tid = threadIdx.x;
    const int b = blockIdx.x * 128 + tid;
    if (b >= B) return;

    const double* W1T = P + oW1T;
    const double* B1v = P + oB1;
    const double* W2  = P + oW2;
    const double* B2v = P + oB2;
    const double* W3  = P + oW3;
    const double* B3v = P + oB3;
    const double* W4  = P + oW4;
    const double* B4v = P + oB4;

    double ys = (double)y0[b * 3 + 0];
    double yi = (double)y0[b * 3 + 1];
    double yr = (double)y0[b * 3 + 2];
    const double be = (double)beta[b];
    const double ga = (double)gamma[b];

    store_softmax(out, (size_t)b * 3, (float)ys, (float)yi, (float)yr);

    #pragma unroll 1
    for (int t = 0; t < T - 1; ++t) {
        double dt = (double)tspan[t + 1] - (double)tspan[t];

        double ks0 = 0.0, ks1 = 0.0, ks2 = 0.0;
        double zs = ys, zi = yi, zr = yr;

        #pragma unroll 1
        for (int st = 0; st < 4; ++st) {
            // ---- L1: 5 -> 64; dynamic j loop, result to LDS (f32) ----
            #pragma unroll 2
            for (int j = 0; j < 64; ++j) {
                const double* w = W1T + j * 5;
                double ta = fma(w[0], zs, B1v[j]);
                double tb = w[2] * zr;
                ta = fma(w[1], zi, ta);
                tb = fma(w[3], be, tb);
                ta = fma(w[4], ga, ta);
                hbuf[j][tid] = tanhf((float)(ta + tb));
            }

            double acc3[64];
            #pragma unroll
            for (int j = 0; j < 64; ++j) acc3[j] = B3v[j];

            // ---- L2+L3: 64 -> 128 -> 64 in 8 tiles of 16 ----
            #pragma unroll 1
            for (int c = 0; c < 8; ++c) {
                double h2[16];
                #pragma unroll
                for (int k = 0; k < 16; ++k) h2[k] = B2v[c * 16 + k];

                #pragma unroll 4
                for (int i = 0; i < 64; ++i) {
                    double hv = (double)hbuf[i][tid];      // 1 read+cvt per 16 FMA
                    const double* w = W2 + i * 128 + c * 16;
                    #pragma unroll
                    for (int k = 0; k < 16; ++k)
                        h2[k] = fma(w[k], hv, h2[k]);
                }

                #pragma unroll
                for (int k = 0; k < 16; ++k)
                    h2[k] = (double)tanhf((float)h2[k]);

                #pragma unroll
                for (int k = 0; k < 16; ++k) {
                    const double* w3 = W3 + (size_t)(c * 16 + k) * 64;
                    #pragma unroll
                    for (int j = 0; j < 64; ++j)
                        acc3[j] = fma(w3[j], h2[k], acc3[j]);
                }
            }

            // ---- L4: 64 -> 3; LDS round-trip shrinks I-footprint ----
            #pragma unroll
            for (int j = 0; j < 64; ++j) hbuf[j][tid] = (float)acc3[j];

            double e0 = B4v[0], e1 = B4v[1], e2 = B4v[2];
            #pragma unroll 2
            for (int j = 0; j < 64; ++j) {
                double h = (double)tanhf(hbuf[j][tid]);
                const double* w4 = W4 + j * 3;
                e0 = fma(w4[0], h, e0);
                e1 = fma(w4[1], h, e1);
                e2 = fma(w4[2], h, e2);
            }

            double w = (st == 1 || st == 2) ? 2.0 : 1.0;
            ks0 = fma(w, e0, ks0);
            ks1 = fma(w, e1, ks1);
            ks2 = fma(w, e2, ks2);
            double a = (st < 2) ? 0.5 * dt : dt;
            zs = fma(a, e0, ys);
            zi = fma(a, e1, yi);
            zr = fma(a, e2, yr);
        }

        double c6 = dt * (1.0 / 6.0);
        ys = fma(c6, ks0, ys);
        yi = fma(c6, ks1, yi);
        yr = fma(c6, ks2, yr);

        store_softmax(out, ((size_t)(t + 1) * B + b) * 3, (float)ys, (float)yi, (float)yr);
    }
}

// widen all params to fp64 in ws; W1 transposed to [64][5], rest original.
__global__ void stage_params_kernel(
    const float* __restrict__ W1, const float* __restrict__ b1,
    const float* __restrict__ W2, const float* __restrict__ b2,
    const float* __restrict__ W3, const float* __restrict__ b3,
    const float* __restrict__ W4, const float* __restrict__ b4,
    double* __restrict__ P)
{
    int idx = blockIdx.x * blockDim.x + threadIdx.x;
    if (idx >= NTOT) return;
    float v;
    if (idx < oB1)       { int u = idx - oW1T; int j = u / 5; int q = u % 5; v = W1[q * 64 + j]; }
    else if (idx < oW2)  v = b1[idx - oB1];
    else if (idx < oB2)  v = W2[idx - oW2];
    else if (idx < oW3)  v = b2[idx - oB2];
    else if (idx < oB3)  v = W3[idx - oW3];
    else if (idx < oW4)  v = b3[idx - oB3];
    else if (idx < oB4)  v = W4[idx - oW4];
    else                 v = b4[idx - oB4];
    P[idx] = (double)v;
}

extern "C" void kernel_launch(void* const* d_in, const int* in_sizes, int n_in,
                              void* d_out, int out_size, void* d_ws, size_t ws_size,
                              hipStream_t stream) {
    const float* y0    = (const float*)d_in[0];
    const float* tspan = (const float*)d_in[1];
    const float* beta  = (const float*)d_in[2];
    const float* gamma = (const float*)d_in[3];
    const float* W1    = (const float*)d_in[4];
    const float* b1    = (const float*)d_in[5];
    const float* W2    = (const float*)d_in[6];
    const float* b2    = (const float*)d_in[7];
    const float* W3    = (const float*)d_in[8];
    const float* b3    = (const float*)d_in[9];
    const float* W4    = (const float*)d_in[10];
    const float* b4    = (const float*)d_in[11];

    int B = in_sizes[0] / 3;
    int T = in_sizes[1];
    float* out = (float*)d_out;

    double* P = (double*)d_ws;
    stage_params_kernel<<<(NTOT + 255) / 256, 256, 0, stream>>>(
        W1, b1, W2, b2, W3, b3, W4, b4, P);

    int blocks = (B + 127) / 128;
    sir_rk4_kernel<<<blocks, 128, 0, stream>>>(
        y0, tspan, beta, gamma, P, out, B, T);
}